// Round 9
// baseline (273.583 us; speedup 1.0000x reference)
//
#include <hip/hip_runtime.h>
#include <hip/hip_fp16.h>
#include <math.h>

#define N_NODES 50000
#define N_EDGES 800000
#define E2 (N_EDGES + N_NODES)   // 850000
#define HEADS 5
#define C1 32
#define F1 160

#define NBL 128                  // edge-pass blocks in k_init
#define CH  6641                 // 128*6641 >= E2
#define GRID_H1 (N_NODES/4)      // 12500 h1 blocks in k_init
#define SC_NB 196                // ceil(N_NODES/256) scan blocks

// head-phased k_agg1 / k_ep geometry: 8 lanes per (node,head), 32 nodes/block
#define AGG1_NPB 32
#define AGG1_NB  1563            // ceil(N_NODES/32)

static constexpr size_t alignup(size_t x){ return (x + 255) & ~size_t(255); }
static constexpr size_t OFF_SCAL  = 0;                                           // 64 f
static constexpr size_t OFF_DEG   = alignup(OFF_SCAL + 64*4);                    // N i
static constexpr size_t OFF_CUR   = alignup(OFF_DEG  + (size_t)N_NODES*4);       // N i
static constexpr size_t OFF_EAS   = alignup(OFF_CUR  + (size_t)N_NODES*4);       // NBL f
static constexpr size_t OFF_PART  = alignup(OFF_EAS  + (size_t)NBL*4);           // SC_NB i
static constexpr size_t OFF_PPREF = alignup(OFF_PART + (size_t)SC_NB*4);         // 256 i
static constexpr size_t OFF_OFFS  = alignup(OFF_PPREF+ (size_t)256*4);           // N+1 i
static constexpr size_t OFF_EDG   = alignup(OFF_OFFS + (size_t)(N_NODES+1)*4);   // E2 u32
static constexpr size_t OFF_AS16  = alignup(OFF_EDG  + (size_t)E2*4);            // [N][8] fp16
static constexpr size_t OFF_AD16  = alignup(OFF_AS16 + (size_t)N_NODES*8*2);     // [N][8] fp16
static constexpr size_t OFF_G16   = alignup(OFF_AD16 + (size_t)N_NODES*8*2);     // [N][8] half (16B rows)
static constexpr size_t OFF_AD2P  = alignup(OFF_G16  + (size_t)N_NODES*8*2);     // N*8 f
static constexpr size_t OFF_H1Q   = alignup(OFF_AD2P + (size_t)N_NODES*8*4);     // [H][N][32] fp8
static constexpr size_t OFF_P01   = alignup(OFF_H1Q  + (size_t)N_NODES*F1);      // EP[h=0,1]: 2*E2 u32
static constexpr size_t OFF_P2    = alignup(OFF_P01  + (size_t)2*E2*4);          // EP[h=2,3,4]: 3*E2 u32
static constexpr size_t OFF_H2P   = alignup(OFF_P2   + (size_t)3*E2*4);          // [H][N][5] f h2 partials

typedef float vf2 __attribute__((ext_vector_type(2)));
__device__ __forceinline__ float4 fp8x4_to_f32(unsigned int r){
  vf2 lo = __builtin_amdgcn_cvt_pk_f32_fp8((int)r, false);
  vf2 hi = __builtin_amdgcn_cvt_pk_f32_fp8((int)r, true);
  return make_float4(lo.x, lo.y, hi.x, hi.y);
}

// ---- zero deg (workspace is poison-filled) ----
__global__ __launch_bounds__(256) void k_zero(int* __restrict__ deg){
  int i = blockIdx.x*256 + threadIdx.x;
  if (i < N_NODES) deg[i] = 0;
}

// ---- fused: layer-1 projection (fp8 h1, HEAD-MAJOR) + global-atomic degree hist ----
__global__ __launch_bounds__(320) void k_init(const float* __restrict__ x, const float* __restrict__ W1,
                       const float* __restrict__ as1w, const float* __restrict__ ad1w,
                       unsigned short* __restrict__ h1qh, __half* __restrict__ as16, __half* __restrict__ ad16,
                       const int* __restrict__ dst, const float* __restrict__ ea,
                       int* __restrict__ deg, float* __restrict__ easum){
  __shared__ float sW[5*F1];
  int t = threadIdx.x;
  if (blockIdx.x < GRID_H1){
    for (int k = t; k < 5*F1; k += 320) sW[k] = W1[k];
    __syncthreads();
    int nl = t / 80;
    int c  = t - nl*80;
    int n  = blockIdx.x*4 + nl;
    int c0 = 2*c;
    float hv0 = 0.f, hv1 = 0.f;
    #pragma unroll
    for (int f = 0; f < 5; f++){
      float xv = x[n*5 + f];
      hv0 += xv * sW[f*F1 + c0];
      hv1 += xv * sW[f*F1 + c0 + 1];
    }
    int pk = __builtin_amdgcn_cvt_pk_fp8_f32(hv0, hv1, 0, false);
    int hh = c >> 4, pp = c & 15;
    h1qh[(size_t)hh*(N_NODES*16) + n*16 + pp] = (unsigned short)(pk & 0xFFFF);
    float vs = hv0*as1w[c0] + hv1*as1w[c0+1];
    float vd = hv0*ad1w[c0] + hv1*ad1w[c0+1];
    #pragma unroll
    for (int m = 8; m >= 1; m >>= 1){
      vs += __shfl_xor(vs, m, 64);
      vd += __shfl_xor(vd, m, 64);
    }
    if ((c & 15) == 0){
      int h = c >> 4;
      as16[n*8 + h] = __float2half(vs);
      ad16[n*8 + h] = __float2half(vd);
    }
  } else {
    float* wsum = (float*)sW;
    int b = blockIdx.x - GRID_H1;
    int e0 = b*CH, e1 = min(e0 + CH, E2);
    float s = 0.f;
    for (int e = e0 + t; e < e1; e += 320){
      int d;
      if (e < N_EDGES){ d = dst[e]; s += ea[e]; }
      else d = e - N_EDGES;
      atomicAdd(&deg[d], 1);
    }
    #pragma unroll
    for (int m = 1; m < 64; m <<= 1) s += __shfl_xor(s, m, 64);
    if ((t & 63) == 0) wsum[t >> 6] = s;
    __syncthreads();
    if (t == 0) easum[b] = wsum[0] + wsum[1] + wsum[2] + wsum[3] + wsum[4];
  }
}

// ---- scan stage A: per-256-chunk degree sums ----
__global__ __launch_bounds__(256) void k_scanA(const int* __restrict__ deg, int* __restrict__ part){
  int i = blockIdx.x*256 + threadIdx.x;
  int v = (i < N_NODES) ? deg[i] : 0;
  #pragma unroll
  for (int m = 1; m < 64; m <<= 1) v += __shfl_xor(v, m, 64);
  __shared__ int sh[4];
  if ((threadIdx.x & 63) == 0) sh[threadIdx.x >> 6] = v;
  __syncthreads();
  if (threadIdx.x == 0) part[blockIdx.x] = sh[0] + sh[1] + sh[2] + sh[3];
}

// ---- scan stage B: scan SC_NB partials + scalar prep (1 block) ----
__global__ __launch_bounds__(256) void k_scanB(const int* __restrict__ part, int* __restrict__ ppref,
                      int* __restrict__ offs, const float* __restrict__ easum,
                      const float* __restrict__ We1, const float* __restrict__ ae1,
                      const float* __restrict__ We2, const float* __restrict__ ae2,
                      float* __restrict__ scal){
  __shared__ int sp[256];
  __shared__ float sh_ea[NBL];
  int t = threadIdx.x;
  if (t < NBL) sh_ea[t] = easum[t];
  if (t >= 200 && t < 200 + HEADS){
    int h = t - 200;
    float s = 0.f;
    for (int c = 0; c < C1; c++) s += We1[h*C1 + c] * ae1[h*C1 + c];
    scal[2 + h] = s;
    scal[7 + h] = We2[h] * ae2[h];
  }
  int v = (t < SC_NB) ? part[t] : 0;
  sp[t] = v;
  __syncthreads();
  if (t == 255){
    float es = 0.f;
    for (int i = 0; i < NBL; i++) es += sh_ea[i];
    scal[1] = es / (float)N_EDGES;
  }
  for (int off = 1; off < 256; off <<= 1){
    int u = (t >= off) ? sp[t - off] : 0;
    __syncthreads();
    sp[t] += u;
    __syncthreads();
  }
  if (t < SC_NB) ppref[t] = sp[t] - v;
  if (t == 0) offs[N_NODES] = E2;
}

// ---- scan stage C: offs[n] = ppref[blk] + local exclusive scan; cursor copy ----
__global__ __launch_bounds__(256) void k_scanC(const int* __restrict__ deg, const int* __restrict__ ppref,
                      int* __restrict__ offs, int* __restrict__ cursor){
  __shared__ int sp[256];
  int b = blockIdx.x, t = threadIdx.x;
  int i = b*256 + t;
  int v = (i < N_NODES) ? deg[i] : 0;
  sp[t] = v;
  __syncthreads();
  for (int off = 1; off < 256; off <<= 1){
    int u = (t >= off) ? sp[t - off] : 0;
    __syncthreads();
    sp[t] += u;
    __syncthreads();
  }
  int P = ppref[b] + sp[t] - v;
  if (i < N_NODES){ offs[i] = P; cursor[i] = P; }
}

// ---- direct atomic scatter into dst-grouped edge2 (order within node arbitrary) ----
__global__ __launch_bounds__(256) void k_scat2(const int* __restrict__ src, const int* __restrict__ dst,
                       const float* __restrict__ ea, const float* __restrict__ scal,
                       int* __restrict__ cursor, unsigned int* __restrict__ edge2){
  int e = blockIdx.x*256 + threadIdx.x;
  if (e >= E2) return;
  float mean = scal[1];
  int d, s; float a;
  if (e < N_EDGES){ d = dst[e]; s = src[e]; a = ea[e]; }
  else { d = s = e - N_EDGES; a = mean; }
  int pos = atomicAdd(&cursor[d], 1);
  edge2[pos] = (unsigned int)s |
               ((unsigned int)__half_as_ushort(__float2half(a)) << 16);
}

// ---- per-edge attention numerator precompute (all 5 heads, coalesced) ----
__global__ __launch_bounds__(256) void k_ep(const int* __restrict__ offs,
                      const unsigned int* __restrict__ edge2,
                      const __half* __restrict__ as16, const __half* __restrict__ ad16,
                      const float* __restrict__ scal,
                      unsigned int* __restrict__ P01, unsigned int* __restrict__ P2){
  int gl = threadIdx.x >> 3;
  int q  = threadIdx.x & 7;
  int n  = blockIdx.x*AGG1_NPB + gl;
  if (n >= N_NODES) return;
  union { uint4 u; __half2 h[4]; } AD; AD.u = *(const uint4*)(ad16 + (size_t)n*8);
  float ad0 = __low2float(AD.h[0]), ad1 = __high2float(AD.h[0]);
  float ad2 = __low2float(AD.h[1]), ad3 = __high2float(AD.h[1]);
  float ad4 = __low2float(AD.h[2]);
  float wd0 = scal[2], wd1 = scal[3], wd2 = scal[4], wd3 = scal[5], wd4 = scal[6];
  int j0 = offs[n], j1 = offs[n + 1];
  for (int j = j0 + q; j < j1; j += 8){
    unsigned int e = edge2[j];
    unsigned int lo = e & 0xFFFFu;
    int s = (int)lo;
    float c = __half2float(__ushort_as_half((unsigned short)(e >> 16)));
    union { uint4 u; __half2 h[4]; } AS; AS.u = *(const uint4*)(as16 + (size_t)s*8);
    float l0 = __low2float(AS.h[0])  + ad0 + c*wd0;  l0 = fminf(fmaxf(l0, 0.2f*l0), 10.f);
    float l1 = __high2float(AS.h[0]) + ad1 + c*wd1;  l1 = fminf(fmaxf(l1, 0.2f*l1), 10.f);
    float l2 = __low2float(AS.h[1])  + ad2 + c*wd2;  l2 = fminf(fmaxf(l2, 0.2f*l2), 10.f);
    float l3 = __high2float(AS.h[1]) + ad3 + c*wd3;  l3 = fminf(fmaxf(l3, 0.2f*l3), 10.f);
    float l4 = __low2float(AS.h[2])  + ad4 + c*wd4;  l4 = fminf(fmaxf(l4, 0.2f*l4), 10.f);
    P01[j]                = lo | ((unsigned int)__half_as_ushort(__float2half(__expf(l0))) << 16);
    P01[(size_t)E2 + j]   = lo | ((unsigned int)__half_as_ushort(__float2half(__expf(l1))) << 16);
    P2[j]                 = lo | ((unsigned int)__half_as_ushort(__float2half(__expf(l2))) << 16);
    P2[(size_t)E2 + j]    = lo | ((unsigned int)__half_as_ushort(__float2half(__expf(l3))) << 16);
    P2[(size_t)2*E2 + j]  = lo | ((unsigned int)__half_as_ushort(__float2half(__expf(l4))) << 16);
  }
}

// ---- layer 1 aggregate: HEAD-PHASED + fused h2 partials (plain stores) ----
__global__ __launch_bounds__(256) void k_agg1(const int* __restrict__ offs,
                      const unsigned int* __restrict__ P01, const unsigned int* __restrict__ P2,
                      const unsigned short* __restrict__ h1qh,
                      const float* __restrict__ b1, const float* __restrict__ W2,
                      float* __restrict__ h2part){
  int head = blockIdx.x / AGG1_NB;
  int nb   = blockIdx.x - head*AGG1_NB;
  __shared__ float sW2[C1*HEADS];   // [32 rows][5] of this head's W2 slice
  for (int i = threadIdx.x; i < C1*HEADS; i += 256) sW2[i] = W2[head*C1*HEADS + i];
  __syncthreads();
  int gl   = threadIdx.x >> 3;
  int q    = threadIdx.x & 7;
  int n    = nb*AGG1_NPB + gl;
  if (n >= N_NODES) return;
  const unsigned int* EP = (head < 2) ? (P01 + (size_t)head*E2)
                                      : (P2  + (size_t)(head-2)*E2);
  const unsigned int* h1row = (const unsigned int*)h1qh + (size_t)head*(N_NODES*8) + q;
  int j0 = offs[n], j1 = offs[n + 1];
  float a0 = 0.f, a1 = 0.f, a2 = 0.f, a3 = 0.f, den = 0.f;
  int j = j0;
  for (; j + 7 < j1; j += 8){
    uint4 sa = *(const uint4*)(EP + j);
    uint4 sb = *(const uint4*)(EP + j + 4);
    unsigned int e0 = sa.x, e1 = sa.y, e2v = sa.z, e3 = sa.w;
    unsigned int e4 = sb.x, e5 = sb.y, e6 = sb.z, e7 = sb.w;
    int s0 = e0 & 0xFFFF, s1 = e1 & 0xFFFF, s2 = e2v & 0xFFFF, s3 = e3 & 0xFFFF;
    int s4 = e4 & 0xFFFF, s5 = e5 & 0xFFFF, s6 = e6 & 0xFFFF, s7 = e7 & 0xFFFF;
    unsigned int r0 = h1row[s0*8];
    unsigned int r1 = h1row[s1*8];
    unsigned int r2 = h1row[s2*8];
    unsigned int r3 = h1row[s3*8];
    unsigned int r4 = h1row[s4*8];
    unsigned int r5 = h1row[s5*8];
    unsigned int r6 = h1row[s6*8];
    unsigned int r7 = h1row[s7*8];
    float p0 = __half2float(__ushort_as_half((unsigned short)(e0 >> 16)));
    float p1 = __half2float(__ushort_as_half((unsigned short)(e1 >> 16)));
    float p2 = __half2float(__ushort_as_half((unsigned short)(e2v >> 16)));
    float p3 = __half2float(__ushort_as_half((unsigned short)(e3 >> 16)));
    float p4 = __half2float(__ushort_as_half((unsigned short)(e4 >> 16)));
    float p5 = __half2float(__ushort_as_half((unsigned short)(e5 >> 16)));
    float p6 = __half2float(__ushort_as_half((unsigned short)(e6 >> 16)));
    float p7 = __half2float(__ushort_as_half((unsigned short)(e7 >> 16)));
    den += ((p0 + p1) + (p2 + p3)) + ((p4 + p5) + (p6 + p7));
    float4 f0 = fp8x4_to_f32(r0), f1 = fp8x4_to_f32(r1);
    float4 f2 = fp8x4_to_f32(r2), f3 = fp8x4_to_f32(r3);
    float4 f4 = fp8x4_to_f32(r4), f5 = fp8x4_to_f32(r5);
    float4 f6 = fp8x4_to_f32(r6), f7 = fp8x4_to_f32(r7);
    a0 += p0*f0.x; a1 += p0*f0.y; a2 += p0*f0.z; a3 += p0*f0.w;
    a0 += p1*f1.x; a1 += p1*f1.y; a2 += p1*f1.z; a3 += p1*f1.w;
    a0 += p2*f2.x; a1 += p2*f2.y; a2 += p2*f2.z; a3 += p2*f2.w;
    a0 += p3*f3.x; a1 += p3*f3.y; a2 += p3*f3.z; a3 += p3*f3.w;
    a0 += p4*f4.x; a1 += p4*f4.y; a2 += p4*f4.z; a3 += p4*f4.w;
    a0 += p5*f5.x; a1 += p5*f5.y; a2 += p5*f5.z; a3 += p5*f5.w;
    a0 += p6*f6.x; a1 += p6*f6.y; a2 += p6*f6.z; a3 += p6*f6.w;
    a0 += p7*f7.x; a1 += p7*f7.y; a2 += p7*f7.z; a3 += p7*f7.w;
  }
  for (; j < j1; ++j){
    unsigned int e = EP[j];
    int s = e & 0xFFFF;
    float p = __half2float(__ushort_as_half((unsigned short)(e >> 16)));
    den += p;
    float4 f = fp8x4_to_f32(h1row[s*8]);
    a0 += p*f.x; a1 += p*f.y; a2 += p*f.z; a3 += p*f.w;
  }
  float inv = 1.f / (den + 1e-16f);
  float4 bb = *(const float4*)(b1 + head*C1 + 4*q);
  float v0 = fmaxf(a0*inv + bb.x, 0.f);
  float v1 = fmaxf(a1*inv + bb.y, 0.f);
  float v2 = fmaxf(a2*inv + bb.z, 0.f);
  float v3 = fmaxf(a3*inv + bb.w, 0.f);
  const float* wr = sW2 + (4*q)*HEADS;
  float hh[HEADS];
  #pragma unroll
  for (int h2i = 0; h2i < HEADS; h2i++)
    hh[h2i] = v0*wr[0*HEADS + h2i] + v1*wr[1*HEADS + h2i]
            + v2*wr[2*HEADS + h2i] + v3*wr[3*HEADS + h2i];
  #pragma unroll
  for (int m = 1; m < 8; m <<= 1){
    #pragma unroll
    for (int h2i = 0; h2i < HEADS; h2i++) hh[h2i] += __shfl_xor(hh[h2i], m, 8);
  }
  if (q == 0){
    float* hp = h2part + ((size_t)head*N_NODES + n)*HEADS;
    hp[0] = hh[0]; hp[1] = hh[1]; hp[2] = hh[2]; hp[3] = hh[3]; hp[4] = hh[4];
  }
}

// ---- tiny: sum h2 partials -> packed fp16 G16 (16B rows, h2 only) + ad2p ----
__global__ __launch_bounds__(256) void k_h2b(const float* __restrict__ h2part,
                    const float* __restrict__ adw2,
                    __half* __restrict__ G16, float* __restrict__ ad2p){
  int n = blockIdx.x*256 + threadIdx.x;
  if (n >= N_NODES) return;
  float a0 = 0.f, a1 = 0.f, a2 = 0.f, a3 = 0.f, a4 = 0.f;
  #pragma unroll
  for (int hd = 0; hd < HEADS; hd++){
    const float* hp = h2part + ((size_t)hd*N_NODES + n)*HEADS;
    a0 += hp[0]; a1 += hp[1]; a2 += hp[2]; a3 += hp[3]; a4 += hp[4];
  }
  __half2 g0 = __floats2half2_rn(a0, a1);
  __half2 g1 = __floats2half2_rn(a2, a3);
  __half2 g2 = __floats2half2_rn(a4, 0.f);
  __half2 g3 = __floats2half2_rn(0.f, 0.f);
  *(uint4*)(G16 + (size_t)n*8) = make_uint4(*(unsigned int*)&g0, *(unsigned int*)&g1,
                                            *(unsigned int*)&g2, *(unsigned int*)&g3);
  float4 d0 = make_float4(a0*adw2[0], a1*adw2[1], a2*adw2[2], a3*adw2[3]);
  float4 d1 = make_float4(a4*adw2[4], 0.f, 0.f, 0.f);
  *(float4*)(ad2p + (size_t)n*8)     = d0;
  *(float4*)(ad2p + (size_t)n*8 + 4) = d1;
}

// ---- layer 2: 16-lane-group-per-node softmax aggregate + mean + linear + sigmoid ----
__global__ __launch_bounds__(256) void k_agg2(const int* __restrict__ offs,
                      const unsigned int* __restrict__ edge2,
                      const __half* __restrict__ G16, const float* __restrict__ ad2p,
                      const float* __restrict__ scal, const float* __restrict__ asw2,
                      const float* __restrict__ b2, const float* __restrict__ Wlin,
                      float* __restrict__ out){
  int grp = threadIdx.x >> 4;
  int l16 = threadIdx.x & 15;
  int n = blockIdx.x*16 + grp;
  float adn[HEADS], wd[HEADS], asw[HEADS];
  #pragma unroll
  for (int h = 0; h < HEADS; h++){
    adn[h] = ad2p[n*8 + h]; wd[h] = scal[7 + h]; asw[h] = asw2[h];
  }
  int j0 = offs[n], j1 = offs[n + 1];

  float den[HEADS] = {0,0,0,0,0};
  float ac[HEADS]  = {0,0,0,0,0};
  for (int j = j0 + l16; j < j1; j += 16){
    unsigned int e = edge2[j];
    int s = e & 0xFFFF;
    float c = __half2float(__ushort_as_half((unsigned short)(e >> 16)));
    union { uint4 u; __half2 h[4]; } U; U.u = *(const uint4*)(G16 + (size_t)s*8);
    float2 p01 = __half22float2(U.h[0]);
    float2 p23 = __half22float2(U.h[1]);
    float2 p45 = __half22float2(U.h[2]);
    float hv[HEADS] = {p01.x, p01.y, p23.x, p23.y, p45.x};
    #pragma unroll
    for (int h = 0; h < HEADS; h++){
      float lg = hv[h]*asw[h] + adn[h] + c*wd[h];
      lg = fmaxf(lg, 0.2f*lg);
      lg = fminf(lg, 50.f);
      float p = __expf(lg);
      den[h] += p;
      ac[h]  += p * hv[h];
    }
  }
  #pragma unroll
  for (int m = 1; m < 16; m <<= 1){
    #pragma unroll
    for (int h = 0; h < HEADS; h++){
      den[h] += __shfl_xor(den[h], m, 16);
      ac[h]  += __shfl_xor(ac[h], m, 16);
    }
  }
  if (l16 == 0){
    float v = 0.f;
    #pragma unroll
    for (int h = 0; h < HEADS; h++) v += ac[h] / (den[h] + 1e-16f);
    v = v * (1.f/HEADS) + b2[0];
    v *= Wlin[0];
    out[n] = 1.f / (1.f + __expf(-v));
  }
}

extern "C" void kernel_launch(void* const* d_in, const int* in_sizes, int n_in,
                              void* d_out, int out_size, void* d_ws, size_t ws_size,
                              hipStream_t stream) {
  const float* x    = (const float*)d_in[0];
  const float* ea   = (const float*)d_in[1];
  const int*   src  = (const int*)d_in[2];
  const int*   dst  = (const int*)d_in[3];
  const float* W1   = (const float*)d_in[4];
  const float* as1w = (const float*)d_in[5];
  const float* ad1w = (const float*)d_in[6];
  const float* We1  = (const float*)d_in[7];
  const float* ae1  = (const float*)d_in[8];
  const float* b1   = (const float*)d_in[9];
  const float* W2   = (const float*)d_in[10];
  const float* as2w = (const float*)d_in[11];
  const float* ad2w = (const float*)d_in[12];
  const float* We2  = (const float*)d_in[13];
  const float* ae2  = (const float*)d_in[14];
  const float* b2   = (const float*)d_in[15];
  const float* Wlin = (const float*)d_in[16];

  char* ws = (char*)d_ws;
  float* scal   = (float*)(ws + OFF_SCAL);
  int*   deg    = (int*)  (ws + OFF_DEG);
  int*   cursor = (int*)  (ws + OFF_CUR);
  float* easum  = (float*)(ws + OFF_EAS);
  int*   part   = (int*)  (ws + OFF_PART);
  int*   ppref  = (int*)  (ws + OFF_PPREF);
  int*   offs   = (int*)  (ws + OFF_OFFS);
  unsigned int* edge2 = (unsigned int*)(ws + OFF_EDG);
  unsigned int* P01 = (unsigned int*)(ws + OFF_P01);
  unsigned int* P2  = (unsigned int*)(ws + OFF_P2);
  __half* as16  = (__half*)(ws + OFF_AS16);
  __half* ad16  = (__half*)(ws + OFF_AD16);
  __half* G16   = (__half*)(ws + OFF_G16);
  float* ad2p   = (float*)(ws + OFF_AD2P);
  unsigned short* h1qh = (unsigned short*)(ws + OFF_H1Q);
  float* h2part = (float*)(ws + OFF_H2P);
  float* outp   = (float*)d_out;

  k_zero  <<<SC_NB, 256, 0, stream>>>(deg);
  k_init  <<<GRID_H1 + NBL, 320, 0, stream>>>(x, W1, as1w, ad1w, h1qh, as16, ad16,
                                              dst, ea, deg, easum);
  k_scanA <<<SC_NB, 256, 0, stream>>>(deg, part);
  k_scanB <<<1, 256, 0, stream>>>(part, ppref, offs, easum, We1, ae1, We2, ae2, scal);
  k_scanC <<<SC_NB, 256, 0, stream>>>(deg, ppref, offs, cursor);
  k_scat2 <<<(E2 + 255)/256, 256, 0, stream>>>(src, dst, ea, scal, cursor, edge2);
  k_ep    <<<AGG1_NB, 256, 0, stream>>>(offs, edge2, as16, ad16, scal, P01, P2);

  k_agg1  <<<HEADS*AGG1_NB, 256, 0, stream>>>(offs, P01, P2, h1qh, b1, W2, h2part);
  k_h2b   <<<SC_NB, 256, 0, stream>>>(h2part, ad2w, G16, ad2p);
  k_agg2  <<<N_NODES/16, 256, 0, stream>>>(offs, edge2, G16, ad2p, scal, as2w, b2, Wlin, outp);
}

// Round 10
// 199.838 us; speedup vs baseline: 1.3690x; 1.3690x over previous
//
#include <hip/hip_runtime.h>
#include <hip/hip_fp16.h>
#include <math.h>

#define N_NODES 50000
#define N_EDGES 800000
#define E2 (N_EDGES + N_NODES)   // 850000
#define HEADS 5
#define C1 32
#define F1 160

// counting-sort CSR build (64-node buckets)
#define BSZ 64
#define NBK 782                  // 782*64 = 50048 >= N
#define NBL 128
#define CH  6641                 // 128*6641 >= E2
#define MTOT (NBK*NBL)           // 100096
#define MC  391                  // ceil(MTOT/256)
#define GRID_H1 1563             // projection blocks (32 nodes each)
#define CAP 1408                 // LDS staging cap per 64-node bucket

// head-phased k_agg1 geometry: 8 lanes per (node,head), 32 nodes/block
#define AGG1_NPB 32
#define AGG1_NB  1563            // ceil(N_NODES/32)

static constexpr size_t alignup(size_t x){ return (x + 255) & ~size_t(255); }
static constexpr size_t OFF_SCAL  = 0;                                           // 64 f
static constexpr size_t OFF_H     = alignup(OFF_SCAL + 64*4);                    // MTOT i
static constexpr size_t OFF_EAS   = alignup(OFF_H    + (size_t)MTOT*4);          // NBL f
static constexpr size_t OFF_PART  = alignup(OFF_EAS  + (size_t)NBL*4);           // MC i
static constexpr size_t OFF_PPREF = alignup(OFF_PART + (size_t)MC*4);            // MC i
static constexpr size_t OFF_BST   = alignup(OFF_PPREF+ (size_t)MC*4);            // NBK+1
static constexpr size_t OFF_OFFS  = alignup(OFF_BST  + (size_t)(NBK+1)*4);       // N+1
static constexpr size_t OFF_BPACK = alignup(OFF_OFFS + (size_t)(N_NODES+1)*4);   // E2 int2
static constexpr size_t OFF_EDG   = alignup(OFF_BPACK+ (size_t)E2*8);            // E2 u32
static constexpr size_t OFF_AS16  = alignup(OFF_EDG  + (size_t)E2*4);            // [N][8] fp16 alpha_src coefs
static constexpr size_t OFF_AD16  = alignup(OFF_AS16 + (size_t)N_NODES*8*2);     // [N][8] fp16 alpha_dst coefs
static constexpr size_t OFF_G16   = alignup(OFF_AD16 + (size_t)N_NODES*8*2);     // N*16 half
static constexpr size_t OFF_AD2P  = alignup(OFF_G16  + (size_t)N_NODES*16*2);    // N*8 f
static constexpr size_t OFF_H1Q   = alignup(OFF_AD2P + (size_t)N_NODES*8*4);     // [H][N][32] fp8
static constexpr size_t OFF_P01   = alignup(OFF_H1Q  + (size_t)N_NODES*F1);      // EP[h=0,1]: 2*E2 u32
static constexpr size_t OFF_P2    = alignup(OFF_P01  + (size_t)2*E2*4);          // EP[h=2,3,4]: 3*E2 u32
static constexpr size_t OFF_H2A   = alignup(OFF_P2   + (size_t)3*E2*4);          // [N][5] f h2 accum

typedef float vf2 __attribute__((ext_vector_type(2)));
__device__ __forceinline__ float4 fp8x4_to_f32(unsigned int r){
  vf2 lo = __builtin_amdgcn_cvt_pk_f32_fp8((int)r, false);
  vf2 hi = __builtin_amdgcn_cvt_pk_f32_fp8((int)r, true);
  return make_float4(lo.x, lo.y, hi.x, hi.y);
}

// ---- fused: layer-1 projection (fp8 h1, HEAD-MAJOR, 32 nodes/block) + hist ----
__global__ __launch_bounds__(320) void k_init(const float* __restrict__ x, const float* __restrict__ W1,
                       const float* __restrict__ as1w, const float* __restrict__ ad1w,
                       unsigned short* __restrict__ h1qh, __half* __restrict__ as16, __half* __restrict__ ad16,
                       const int* __restrict__ dst, const float* __restrict__ ea,
                       int* __restrict__ H, float* __restrict__ easum){
  __shared__ float sW[5*F1];
  __shared__ float sx[32*5];
  int t = threadIdx.x;
  if (blockIdx.x < GRID_H1){
    for (int k = t; k < 5*F1; k += 320) sW[k] = W1[k];
    int xb = blockIdx.x*160;
    if (t < 160 && xb + t < N_NODES*5) sx[t] = x[xb + t];
    __syncthreads();
    int nl = t / 80;
    int c  = t - nl*80;
    int c0 = 2*c;
    int hh = c >> 4, pp = c & 15;
    // per-thread W1 columns are loop-invariant
    float w0[5], w1[5];
    #pragma unroll
    for (int f = 0; f < 5; f++){ w0[f] = sW[f*F1 + c0]; w1[f] = sW[f*F1 + c0 + 1]; }
    float aw0 = as1w[c0], aw1 = as1w[c0+1];
    float dw0 = ad1w[c0], dw1 = ad1w[c0+1];
    #pragma unroll
    for (int it = 0; it < 8; it++){
      int n = blockIdx.x*32 + it*4 + nl;
      if (n < N_NODES){
        const float* xv = sx + (it*4 + nl)*5;
        float hv0 = 0.f, hv1 = 0.f;
        #pragma unroll
        for (int f = 0; f < 5; f++){
          hv0 += xv[f] * w0[f];
          hv1 += xv[f] * w1[f];
        }
        int pk = __builtin_amdgcn_cvt_pk_fp8_f32(hv0, hv1, 0, false);
        h1qh[(size_t)hh*(N_NODES*16) + n*16 + pp] = (unsigned short)(pk & 0xFFFF);
        float vs = hv0*aw0 + hv1*aw1;
        float vd = hv0*dw0 + hv1*dw1;
        #pragma unroll
        for (int m = 8; m >= 1; m >>= 1){
          vs += __shfl_xor(vs, m, 64);
          vd += __shfl_xor(vd, m, 64);
        }
        if ((c & 15) == 0){
          int h = c >> 4;
          as16[n*8 + h] = __float2half(vs);
          ad16[n*8 + h] = __float2half(vd);
        }
      }
    }
  } else {
    int* hist = (int*)sW;
    float* wsum = (float*)&hist[NBK + 1];
    for (int k = t; k < NBK; k += 320) hist[k] = 0;
    __syncthreads();
    int b = blockIdx.x - GRID_H1;
    int e0 = b*CH, e1 = min(e0 + CH, E2);
    float s = 0.f;
    for (int e = e0 + t; e < e1; e += 320){
      int d;
      if (e < N_EDGES){ d = dst[e]; s += ea[e]; }
      else d = e - N_EDGES;
      atomicAdd(&hist[d >> 6], 1);
    }
    #pragma unroll
    for (int m = 1; m < 64; m <<= 1) s += __shfl_xor(s, m, 64);
    if ((t & 63) == 0) wsum[t >> 6] = s;
    __syncthreads();
    for (int k = t; k < NBK; k += 320) H[(size_t)k*NBL + b] = hist[k];
    if (t == 0) easum[b] = wsum[0] + wsum[1] + wsum[2] + wsum[3] + wsum[4];
  }
}

// ---- parallel scan, stage 1 (+ h2acc zeroing) ----
__global__ void k_s1(const int* __restrict__ H, int* __restrict__ partial,
                     float* __restrict__ h2acc){
  int i = blockIdx.x*256 + threadIdx.x;
  for (int z = i; z < N_NODES*HEADS; z += MC*256) h2acc[z] = 0.f;
  int v = (i < MTOT) ? H[i] : 0;
  #pragma unroll
  for (int m = 1; m < 64; m <<= 1) v += __shfl_xor(v, m, 64);
  __shared__ int sh[4];
  if ((threadIdx.x & 63) == 0) sh[threadIdx.x >> 6] = v;
  __syncthreads();
  if (threadIdx.x == 0) partial[blockIdx.x] = sh[0] + sh[1] + sh[2] + sh[3];
}

// ---- stage 2: 512-thread scan of MC=391 partials + scalar prep ----
__global__ __launch_bounds__(512) void k_s2p(const int* __restrict__ partial, int* __restrict__ ppref,
                      int* __restrict__ offs, int* __restrict__ bstart,
                      const float* __restrict__ easum,
                      const float* __restrict__ We1, const float* __restrict__ ae1,
                      const float* __restrict__ We2, const float* __restrict__ ae2,
                      float* __restrict__ scal){
  __shared__ int sp[512];
  __shared__ float sh_ea[NBL];
  int t = threadIdx.x;
  if (t < NBL) sh_ea[t] = easum[t];
  if (t >= 448 && t < 448 + HEADS){
    int h = t - 448;
    float s = 0.f;
    for (int c = 0; c < C1; c++) s += We1[h*C1 + c] * ae1[h*C1 + c];
    scal[2 + h] = s;
    scal[7 + h] = We2[h] * ae2[h];
  }
  int v = (t < MC) ? partial[t] : 0;
  sp[t] = v;
  __syncthreads();
  if (t == 511){
    float es = 0.f;
    for (int i = 0; i < NBL; i++) es += sh_ea[i];
    scal[1] = es / (float)N_EDGES;
  }
  for (int off = 1; off < 512; off <<= 1){
    int u = (t >= off) ? sp[t - off] : 0;
    __syncthreads();
    sp[t] += u;
    __syncthreads();
  }
  if (t < MC) ppref[t] = sp[t] - v;
  if (t == 0){ offs[N_NODES] = E2; bstart[NBK] = E2; }
}

// ---- stage 3 ----
__global__ void k_s3(int* __restrict__ H, const int* __restrict__ ppref, int* __restrict__ bstart){
  __shared__ int sp[256];
  int b = blockIdx.x, t = threadIdx.x;
  int i = b*256 + t;
  int v = (i < MTOT) ? H[i] : 0;
  sp[t] = v;
  __syncthreads();
  for (int off = 1; off < 256; off <<= 1){
    int u = (t >= off) ? sp[t - off] : 0;
    __syncthreads();
    sp[t] += u;
    __syncthreads();
  }
  int P = ppref[b] + sp[t] - v;
  if (i < MTOT){
    H[i] = P;
    if (i % NBL == 0) bstart[i / NBL] = P;
  }
}

// ---- scatter into bucket-major packed records (8B/edge) ----
__global__ __launch_bounds__(256) void k_scat(const int* __restrict__ src, const int* __restrict__ dst,
                       const float* __restrict__ ea, const float* __restrict__ scal,
                       const int* __restrict__ H, int2* __restrict__ bpack){
  __shared__ int lofs[NBK];
  int b = blockIdx.x;
  for (int k = threadIdx.x; k < NBK; k += 256) lofs[k] = H[(size_t)k*NBL + b];
  __syncthreads();
  float mean = scal[1];
  int e0 = b*CH, e1 = min(e0 + CH, E2);
  for (int e = e0 + threadIdx.x; e < e1; e += 256){
    int d, s; float a;
    if (e < N_EDGES){ d = dst[e]; s = src[e]; a = ea[e]; }
    else { d = s = e - N_EDGES; a = mean; }
    int pos = atomicAdd(&lofs[d >> 6], 1);
    bpack[pos] = make_int2(s | ((d & 63) << 16), __float_as_int(a));
  }
}

// ---- per-bucket counting sort -> offs, edge2 + FUSED per-edge logit/exp ----
__global__ __launch_bounds__(256) void k_final2(const int* __restrict__ bstart,
                        const int2* __restrict__ bpack,
                        const __half* __restrict__ as16, const __half* __restrict__ ad16,
                        const float* __restrict__ scal,
                        int* __restrict__ offs, unsigned int* __restrict__ edge2,
                        unsigned int* __restrict__ P01, unsigned int* __restrict__ P2){
  __shared__ int cnt[BSZ], cur[BSZ];
  __shared__ unsigned int s_edge[CAP];
  __shared__ unsigned char s_d6[CAP];
  __shared__ float sAd[HEADS][BSZ];
  int k = blockIdx.x, t = threadIdx.x;
  int base = k*BSZ;
  if (t < BSZ){
    cnt[t] = 0;
    int n = base + t;
    uint4 adu = make_uint4(0,0,0,0);
    if (n < N_NODES) adu = *(const uint4*)(ad16 + (size_t)n*8);
    union { uint4 u; __half2 h[4]; } AD; AD.u = adu;
    sAd[0][t] = __low2float(AD.h[0]); sAd[1][t] = __high2float(AD.h[0]);
    sAd[2][t] = __low2float(AD.h[1]); sAd[3][t] = __high2float(AD.h[1]);
    sAd[4][t] = __low2float(AD.h[2]);
  }
  __syncthreads();
  int r0 = bstart[k], r1 = bstart[k + 1];
  int sz = r1 - r0;
  for (int j = r0 + t; j < r1; j += 256) atomicAdd(&cnt[(bpack[j].x >> 16) & 63], 1);
  __syncthreads();
  if (t == 0){
    int run = 0;
    for (int i = 0; i < BSZ; i++){ int c = cnt[i]; cnt[i] = run; cur[i] = run; run += c; }
  }
  __syncthreads();
  if (t < BSZ){
    int n = base + t;
    if (n < N_NODES) offs[n] = r0 + cnt[t];
  }
  float wd0 = scal[2], wd1 = scal[3], wd2 = scal[4], wd3 = scal[5], wd4 = scal[6];
  if (sz <= CAP){
    for (int j = r0 + t; j < r1; j += 256){
      int2 v = bpack[j];
      int d6 = (v.x >> 16) & 63;
      int lp = atomicAdd(&cur[d6], 1);
      s_edge[lp] = (unsigned int)(v.x & 0xFFFF) |
                   ((unsigned int)__half_as_ushort(__float2half(__int_as_float(v.y))) << 16);
      s_d6[lp] = (unsigned char)d6;
    }
    __syncthreads();
    for (int i = t; i < sz; i += 256){
      unsigned int e = s_edge[i];
      unsigned int lo = e & 0xFFFFu;
      int s = (int)lo;
      int d6 = s_d6[i];
      float c = __half2float(__ushort_as_half((unsigned short)(e >> 16)));
      union { uint4 u; __half2 h[4]; } AS; AS.u = *(const uint4*)(as16 + (size_t)s*8);
      float l0 = __low2float(AS.h[0])  + sAd[0][d6] + c*wd0;  l0 = fminf(fmaxf(l0, 0.2f*l0), 10.f);
      float l1 = __high2float(AS.h[0]) + sAd[1][d6] + c*wd1;  l1 = fminf(fmaxf(l1, 0.2f*l1), 10.f);
      float l2 = __low2float(AS.h[1])  + sAd[2][d6] + c*wd2;  l2 = fminf(fmaxf(l2, 0.2f*l2), 10.f);
      float l3 = __high2float(AS.h[1]) + sAd[3][d6] + c*wd3;  l3 = fminf(fmaxf(l3, 0.2f*l3), 10.f);
      float l4 = __low2float(AS.h[2])  + sAd[4][d6] + c*wd4;  l4 = fminf(fmaxf(l4, 0.2f*l4), 10.f);
      unsigned int p0 = (unsigned int)__half_as_ushort(__float2half(__expf(l0)));
      unsigned int p1 = (unsigned int)__half_as_ushort(__float2half(__expf(l1)));
      unsigned int p2 = (unsigned int)__half_as_ushort(__float2half(__expf(l2)));
      unsigned int p3 = (unsigned int)__half_as_ushort(__float2half(__expf(l3)));
      unsigned int p4 = (unsigned int)__half_as_ushort(__float2half(__expf(l4)));
      int pos = r0 + i;
      edge2[pos]               = e;
      P01[pos]                 = lo | (p0 << 16);
      P01[(size_t)E2 + pos]    = lo | (p1 << 16);
      P2[pos]                  = lo | (p2 << 16);
      P2[(size_t)E2 + pos]     = lo | (p3 << 16);
      P2[(size_t)2*E2 + pos]   = lo | (p4 << 16);
    }
  } else {
    for (int j = r0 + t; j < r1; j += 256){
      int2 v = bpack[j];
      int d6 = (v.x >> 16) & 63;
      int pos = r0 + atomicAdd(&cur[d6], 1);
      int s = v.x & 0xFFFF;
      float c = __int_as_float(v.y);
      unsigned int lo = (unsigned int)s;
      unsigned int e = lo | ((unsigned int)__half_as_ushort(__float2half(c)) << 16);
      union { uint4 u; __half2 h[4]; } AS; AS.u = *(const uint4*)(as16 + (size_t)s*8);
      float l0 = __low2float(AS.h[0])  + sAd[0][d6] + c*wd0;  l0 = fminf(fmaxf(l0, 0.2f*l0), 10.f);
      float l1 = __high2float(AS.h[0]) + sAd[1][d6] + c*wd1;  l1 = fminf(fmaxf(l1, 0.2f*l1), 10.f);
      float l2 = __low2float(AS.h[1])  + sAd[2][d6] + c*wd2;  l2 = fminf(fmaxf(l2, 0.2f*l2), 10.f);
      float l3 = __high2float(AS.h[1]) + sAd[3][d6] + c*wd3;  l3 = fminf(fmaxf(l3, 0.2f*l3), 10.f);
      float l4 = __low2float(AS.h[2])  + sAd[4][d6] + c*wd4;  l4 = fminf(fmaxf(l4, 0.2f*l4), 10.f);
      edge2[pos]               = e;
      P01[pos]                 = lo | ((unsigned int)__half_as_ushort(__float2half(__expf(l0))) << 16);
      P01[(size_t)E2 + pos]    = lo | ((unsigned int)__half_as_ushort(__float2half(__expf(l1))) << 16);
      P2[pos]                  = lo | ((unsigned int)__half_as_ushort(__float2half(__expf(l2))) << 16);
      P2[(size_t)E2 + pos]     = lo | ((unsigned int)__half_as_ushort(__float2half(__expf(l3))) << 16);
      P2[(size_t)2*E2 + pos]   = lo | ((unsigned int)__half_as_ushort(__float2half(__expf(l4))) << 16);
    }
  }
}

// ---- layer 1 aggregate: HEAD-PHASED + fused h2 partial accumulation ----
__global__ __launch_bounds__(256) void k_agg1(const int* __restrict__ offs,
                      const unsigned int* __restrict__ P01, const unsigned int* __restrict__ P2,
                      const unsigned short* __restrict__ h1qh,
                      const float* __restrict__ b1, const float* __restrict__ W2,
                      float* __restrict__ h2acc){
  int head = blockIdx.x / AGG1_NB;
  int nb   = blockIdx.x - head*AGG1_NB;
  __shared__ float sW2[C1*HEADS];   // [32 rows][5] of this head's W2 slice
  for (int i = threadIdx.x; i < C1*HEADS; i += 256) sW2[i] = W2[head*C1*HEADS + i];
  __syncthreads();
  int gl   = threadIdx.x >> 3;
  int q    = threadIdx.x & 7;
  int n    = nb*AGG1_NPB + gl;
  if (n >= N_NODES) return;
  const unsigned int* EP = (head < 2) ? (P01 + (size_t)head*E2)
                                      : (P2  + (size_t)(head-2)*E2);
  const unsigned int* h1row = (const unsigned int*)h1qh + (size_t)head*(N_NODES*8) + q;
  int j0 = offs[n], j1 = offs[n + 1];
  float a0 = 0.f, a1 = 0.f, a2 = 0.f, a3 = 0.f, den = 0.f;
  int j = j0;
  for (; j + 7 < j1; j += 8){
    uint4 sa = *(const uint4*)(EP + j);
    uint4 sb = *(const uint4*)(EP + j + 4);
    unsigned int e0 = sa.x, e1 = sa.y, e2v = sa.z, e3 = sa.w;
    unsigned int e4 = sb.x, e5 = sb.y, e6 = sb.z, e7 = sb.w;
    int s0 = e0 & 0xFFFF, s1 = e1 & 0xFFFF, s2 = e2v & 0xFFFF, s3 = e3 & 0xFFFF;
    int s4 = e4 & 0xFFFF, s5 = e5 & 0xFFFF, s6 = e6 & 0xFFFF, s7 = e7 & 0xFFFF;
    unsigned int r0 = h1row[s0*8];
    unsigned int r1 = h1row[s1*8];
    unsigned int r2 = h1row[s2*8];
    unsigned int r3 = h1row[s3*8];
    unsigned int r4 = h1row[s4*8];
    unsigned int r5 = h1row[s5*8];
    unsigned int r6 = h1row[s6*8];
    unsigned int r7 = h1row[s7*8];
    float p0 = __half2float(__ushort_as_half((unsigned short)(e0 >> 16)));
    float p1 = __half2float(__ushort_as_half((unsigned short)(e1 >> 16)));
    float p2 = __half2float(__ushort_as_half((unsigned short)(e2v >> 16)));
    float p3 = __half2float(__ushort_as_half((unsigned short)(e3 >> 16)));
    float p4 = __half2float(__ushort_as_half((unsigned short)(e4 >> 16)));
    float p5 = __half2float(__ushort_as_half((unsigned short)(e5 >> 16)));
    float p6 = __half2float(__ushort_as_half((unsigned short)(e6 >> 16)));
    float p7 = __half2float(__ushort_as_half((unsigned short)(e7 >> 16)));
    den += ((p0 + p1) + (p2 + p3)) + ((p4 + p5) + (p6 + p7));
    float4 f0 = fp8x4_to_f32(r0), f1 = fp8x4_to_f32(r1);
    float4 f2 = fp8x4_to_f32(r2), f3 = fp8x4_to_f32(r3);
    float4 f4 = fp8x4_to_f32(r4), f5 = fp8x4_to_f32(r5);
    float4 f6 = fp8x4_to_f32(r6), f7 = fp8x4_to_f32(r7);
    a0 += p0*f0.x; a1 += p0*f0.y; a2 += p0*f0.z; a3 += p0*f0.w;
    a0 += p1*f1.x; a1 += p1*f1.y; a2 += p1*f1.z; a3 += p1*f1.w;
    a0 += p2*f2.x; a1 += p2*f2.y; a2 += p2*f2.z; a3 += p2*f2.w;
    a0 += p3*f3.x; a1 += p3*f3.y; a2 += p3*f3.z; a3 += p3*f3.w;
    a0 += p4*f4.x; a1 += p4*f4.y; a2 += p4*f4.z; a3 += p4*f4.w;
    a0 += p5*f5.x; a1 += p5*f5.y; a2 += p5*f5.z; a3 += p5*f5.w;
    a0 += p6*f6.x; a1 += p6*f6.y; a2 += p6*f6.z; a3 += p6*f6.w;
    a0 += p7*f7.x; a1 += p7*f7.y; a2 += p7*f7.z; a3 += p7*f7.w;
  }
  for (; j < j1; ++j){
    unsigned int e = EP[j];
    int s = e & 0xFFFF;
    float p = __half2float(__ushort_as_half((unsigned short)(e >> 16)));
    den += p;
    float4 f = fp8x4_to_f32(h1row[s*8]);
    a0 += p*f.x; a1 += p*f.y; a2 += p*f.z; a3 += p*f.w;
  }
  float inv = 1.f / (den + 1e-16f);
  float4 bb = *(const float4*)(b1 + head*C1 + 4*q);
  float v0 = fmaxf(a0*inv + bb.x, 0.f);
  float v1 = fmaxf(a1*inv + bb.y, 0.f);
  float v2 = fmaxf(a2*inv + bb.z, 0.f);
  float v3 = fmaxf(a3*inv + bb.w, 0.f);
  const float* wr = sW2 + (4*q)*HEADS;
  float hh[HEADS];
  #pragma unroll
  for (int h2i = 0; h2i < HEADS; h2i++)
    hh[h2i] = v0*wr[0*HEADS + h2i] + v1*wr[1*HEADS + h2i]
            + v2*wr[2*HEADS + h2i] + v3*wr[3*HEADS + h2i];
  #pragma unroll
  for (int m = 1; m < 8; m <<= 1){
    #pragma unroll
    for (int h2i = 0; h2i < HEADS; h2i++) hh[h2i] += __shfl_xor(hh[h2i], m, 8);
  }
  if (q == 0){
    #pragma unroll
    for (int h2i = 0; h2i < HEADS; h2i++)
      atomicAdd(&h2acc[n*HEADS + h2i], hh[h2i]);
  }
}

// ---- tiny: h2acc -> packed fp16 G16 ([0..4]=h2, [5..9]=as2) + ad2p ----
__global__ __launch_bounds__(256) void k_h2b(const float* __restrict__ h2acc,
                    const float* __restrict__ asw2, const float* __restrict__ adw2,
                    __half* __restrict__ G16, float* __restrict__ ad2p){
  int n = blockIdx.x*256 + threadIdx.x;
  if (n >= N_NODES) return;
  float a0 = h2acc[n*HEADS + 0], a1 = h2acc[n*HEADS + 1], a2 = h2acc[n*HEADS + 2];
  float a3 = h2acc[n*HEADS + 3], a4 = h2acc[n*HEADS + 4];
  float s0 = asw2[0], s1 = asw2[1], s2 = asw2[2], s3 = asw2[3], s4 = asw2[4];
  __half2 g0 = __floats2half2_rn(a0, a1);
  __half2 g1 = __floats2half2_rn(a2, a3);
  __half2 g2 = __floats2half2_rn(a4, a0*s0);
  __half2 g3 = __floats2half2_rn(a1*s1, a2*s2);
  __half2 g4 = __floats2half2_rn(a3*s3, a4*s4);
  __half2 z  = __floats2half2_rn(0.f, 0.f);
  uint4 lo = make_uint4(*(unsigned int*)&g0, *(unsigned int*)&g1,
                        *(unsigned int*)&g2, *(unsigned int*)&g3);
  uint4 hi = make_uint4(*(unsigned int*)&g4, *(unsigned int*)&z,
                        *(unsigned int*)&z,  *(unsigned int*)&z);
  *(uint4*)(G16 + (size_t)n*16)     = lo;
  *(uint4*)(G16 + (size_t)n*16 + 8) = hi;
  float4 d0 = make_float4(a0*adw2[0], a1*adw2[1], a2*adw2[2], a3*adw2[3]);
  float4 d1 = make_float4(a4*adw2[4], 0.f, 0.f, 0.f);
  *(float4*)(ad2p + (size_t)n*8)     = d0;
  *(float4*)(ad2p + (size_t)n*8 + 4) = d1;
}

// ---- layer 2: 16-lane-group-per-node softmax aggregate + mean + linear + sigmoid ----
__global__ __launch_bounds__(256) void k_agg2(const int* __restrict__ offs,
                      const unsigned int* __restrict__ edge2,
                      const __half* __restrict__ G16, const float* __restrict__ ad2p,
                      const float* __restrict__ scal,
                      const float* __restrict__ b2, const float* __restrict__ Wlin,
                      float* __restrict__ out){
  int grp = threadIdx.x >> 4;
  int l16 = threadIdx.x & 15;
  int n = blockIdx.x*16 + grp;
  float adn[HEADS], wd[HEADS];
  #pragma unroll
  for (int h = 0; h < HEADS; h++){ adn[h] = ad2p[n*8 + h]; wd[h] = scal[7 + h]; }
  int j0 = offs[n], j1 = offs[n + 1];

  float den[HEADS] = {0,0,0,0,0};
  float ac[HEADS]  = {0,0,0,0,0};
  for (int j = j0 + l16; j < j1; j += 16){
    unsigned int e = edge2[j];
    int s = e & 0xFFFF;
    float c = __half2float(__ushort_as_half((unsigned short)(e >> 16)));
    const __half* gs = G16 + (size_t)s*16;
    union { uint4 u; __half2 h[4]; } U; U.u = *(const uint4*)gs;
    union { uint2 u; __half2 h[2]; } V; V.u = *(const uint2*)(gs + 8);
    float2 p01 = __half22float2(U.h[0]);
    float2 p23 = __half22float2(U.h[1]);
    float2 p45 = __half22float2(U.h[2]);
    float2 p67 = __half22float2(U.h[3]);
    float2 p89 = __half22float2(V.h[0]);
    float hv[HEADS] = {p01.x, p01.y, p23.x, p23.y, p45.x};
    float av[HEADS] = {p45.y, p67.x, p67.y, p89.x, p89.y};
    #pragma unroll
    for (int h = 0; h < HEADS; h++){
      float lg = av[h] + adn[h] + c*wd[h];
      lg = fmaxf(lg, 0.2f*lg);
      lg = fminf(lg, 50.f);
      float p = __expf(lg);
      den[h] += p;
      ac[h]  += p * hv[h];
    }
  }
  #pragma unroll
  for (int m = 1; m < 16; m <<= 1){
    #pragma unroll
    for (int h = 0; h < HEADS; h++){
      den[h] += __shfl_xor(den[h], m, 16);
      ac[h]  += __shfl_xor(ac[h], m, 16);
    }
  }
  if (l16 == 0){
    float v = 0.f;
    #pragma unroll
    for (int h = 0; h < HEADS; h++) v += ac[h] / (den[h] + 1e-16f);
    v = v * (1.f/HEADS) + b2[0];
    v *= Wlin[0];
    out[n] = 1.f / (1.f + __expf(-v));
  }
}

extern "C" void kernel_launch(void* const* d_in, const int* in_sizes, int n_in,
                              void* d_out, int out_size, void* d_ws, size_t ws_size,
                              hipStream_t stream) {
  const float* x    = (const float*)d_in[0];
  const float* ea   = (const float*)d_in[1];
  const int*   src  = (const int*)d_in[2];
  const int*   dst  = (const int*)d_in[3];
  const float* W1   = (const float*)d_in[4];
  const float* as1w = (const float*)d_in[5];
  const float* ad1w = (const float*)d_in[6];
  const float* We1  = (const float*)d_in[7];
  const float* ae1  = (const float*)d_in[8];
  const float* b1   = (const float*)d_in[9];
  const float* W2   = (const float*)d_in[10];
  const float* as2w = (const float*)d_in[11];
  const float* ad2w = (const float*)d_in[12];
  const float* We2  = (const float*)d_in[13];
  const float* ae2  = (const float*)d_in[14];
  const float* b2   = (const float*)d_in[15];
  const float* Wlin = (const float*)d_in[16];

  char* ws = (char*)d_ws;
  float* scal   = (float*)(ws + OFF_SCAL);
  int*   H      = (int*)  (ws + OFF_H);
  float* easum  = (float*)(ws + OFF_EAS);
  int*   part   = (int*)  (ws + OFF_PART);
  int*   ppref  = (int*)  (ws + OFF_PPREF);
  int*   bstart = (int*)  (ws + OFF_BST);
  int*   offs   = (int*)  (ws + OFF_OFFS);
  int2*  bpack  = (int2*) (ws + OFF_BPACK);
  unsigned int* edge2 = (unsigned int*)(ws + OFF_EDG);
  unsigned int* P01 = (unsigned int*)(ws + OFF_P01);
  unsigned int* P2  = (unsigned int*)(ws + OFF_P2);
  __half* as16  = (__half*)(ws + OFF_AS16);
  __half* ad16  = (__half*)(ws + OFF_AD16);
  __half* G16   = (__half*)(ws + OFF_G16);
  float* ad2p   = (float*)(ws + OFF_AD2P);
  unsigned short* h1qh = (unsigned short*)(ws + OFF_H1Q);
  float* h2acc  = (float*)(ws + OFF_H2A);
  float* outp   = (float*)d_out;

  k_init   <<<GRID_H1 + NBL, 320, 0, stream>>>(x, W1, as1w, ad1w, h1qh, as16, ad16,
                                               dst, ea, H, easum);
  k_s1     <<<MC, 256, 0, stream>>>(H, part, h2acc);
  k_s2p    <<<1, 512, 0, stream>>>(part, ppref, offs, bstart, easum, We1, ae1, We2, ae2, scal);
  k_s3     <<<MC, 256, 0, stream>>>(H, ppref, bstart);
  k_scat   <<<NBL, 256, 0, stream>>>(src, dst, ea, scal, H, bpack);
  k_final2 <<<NBK, 256, 0, stream>>>(bstart, bpack, as16, ad16, scal, offs, edge2, P01, P2);

  k_agg1   <<<HEADS*AGG1_NB, 256, 0, stream>>>(offs, P01, P2, h1qh, b1, W2, h2acc);
  k_h2b    <<<(N_NODES + 255)/256, 256, 0, stream>>>(h2acc, as2w, ad2w, G16, ad2p);
  k_agg2   <<<N_NODES/16, 256, 0, stream>>>(offs, edge2, G16, ad2p, scal, b2, Wlin, outp);
}